// Round 5
// baseline (280.243 us; speedup 1.0000x reference)
//
#include <hip/hip_runtime.h>
#include <math.h>

// ---------------------------------------------------------------------------
// EncoderLayer: B=2,S=2048,D=768,H=12,DK=64,DFF=3072
// bf16 MFMA (16x16x32) for all matmuls, fp32 accumulate + fp32 pointwise.
// ---------------------------------------------------------------------------

using bf16   = __bf16;
using bf16x8 = __attribute__((ext_vector_type(8))) __bf16;
using bf16x4 = __attribute__((ext_vector_type(4))) __bf16;
using f32x4  = __attribute__((ext_vector_type(4))) float;

constexpr int S_   = 2048;
constexpr int D_   = 768;
constexpr int DFF_ = 3072;
constexpr int M_   = 4096;   // B*S
constexpr int BH_  = 24;     // B*H

__device__ __forceinline__ f32x4 mfma16(bf16x8 a, bf16x8 b, f32x4 c) {
    return __builtin_amdgcn_mfma_f32_16x16x32_bf16(a, b, c, 0, 0, 0);
}

// ---------------------------------------------------------------------------
// pack x (fp32 -> bf16), 4 elems/thread
// ---------------------------------------------------------------------------
__global__ __launch_bounds__(256)
void pack_x_kernel(const float* __restrict__ x, bf16* __restrict__ xb) {
    const int i = blockIdx.x * 256 + threadIdx.x;
    float4 v = ((const float4*)x)[i];
    bf16x4 o;
    o[0] = (bf16)v.x; o[1] = (bf16)v.y; o[2] = (bf16)v.z; o[3] = (bf16)v.w;
    ((bf16x4*)xb)[i] = o;
}

// ---------------------------------------------------------------------------
// ALL weight transposes in one launch: in [K][N] fp32 -> out [N][K] bf16.
// 64x64 tiles, flat block index -> (matrix, tile).
// ---------------------------------------------------------------------------
__global__ __launch_bounds__(256)
void wt_all_kernel(const float* __restrict__ Wq, const float* __restrict__ Wk,
                   const float* __restrict__ Wv, const float* __restrict__ Wo,
                   const float* __restrict__ W1, const float* __restrict__ W2,
                   bf16* __restrict__ Wqkvt, bf16* __restrict__ Wot,
                   bf16* __restrict__ W1t, bf16* __restrict__ W2t) {
    int bid = blockIdx.x;
    const float* in; bf16* out; int K, N, t;
    if (bid < 576) {                       // Wq/Wk/Wv/Wo: 144 tiles each
        int m = bid / 144; t = bid % 144; K = 768; N = 768;
        in  = (m == 0) ? Wq : (m == 1) ? Wk : (m == 2) ? Wv : Wo;
        out = (m == 3) ? Wot : Wqkvt + (size_t)m * 768 * 768;
    } else if (bid < 1152) {               // W1: [768][3072] -> [3072][768]
        t = bid - 576; K = 768; N = 3072; in = W1; out = W1t;
    } else {                               // W2: [3072][768] -> [768][3072]
        t = bid - 1152; K = 3072; N = 768; in = W2; out = W2t;
    }
    const int ntx = N / 64;
    const int n0 = (t % ntx) * 64, k0 = (t / ntx) * 64;

    __shared__ __align__(16) bf16 T[64][72];
    const int tt = threadIdx.x;
    const int r  = tt >> 2, c0 = (tt & 3) * 16;
    const float* src = in + (size_t)(k0 + r) * N + n0 + c0;
#pragma unroll
    for (int j = 0; j < 16; j += 4) {
        float4 v = *(const float4*)(src + j);
        T[r][c0 + j + 0] = (bf16)v.x;
        T[r][c0 + j + 1] = (bf16)v.y;
        T[r][c0 + j + 2] = (bf16)v.z;
        T[r][c0 + j + 3] = (bf16)v.w;
    }
    __syncthreads();
    bf16x8 o0, o1;
#pragma unroll
    for (int j = 0; j < 8; j++) { o0[j] = T[c0 + j][r]; o1[j] = T[c0 + 8 + j][r]; }
    bf16* dst = out + (size_t)(n0 + r) * K + k0 + c0;
    *(bf16x8*)(dst)     = o0;
    *(bf16x8*)(dst + 8) = o1;
}

// ---------------------------------------------------------------------------
// GEMM: C = A[M,K] @ Bt[N,K]^T, BMxBN tile, BK=64, 4 waves in WRxWC grid.
// Register-staged, FRAGMENT-MAJOR LDS layout:
//   element (r, k) of the 64-wide K-tile lives at LDS 16B-unit
//     ((r>>4)*2 + (k>>5))*64 + ((k>>3)&3)*16 + (r&15)
//   so every ds_read_b128 of an MFMA fragment is frag*1024B + lane*16B
//   -> fully linear, ZERO bank conflicts (writes are bijective per 1KB too).
// Pipeline per K-step: barrier / ds_write regs / barrier / issue next global
// loads (in flight under compute) / ds_read frags + MFMA.
// EPI: 0=QKV (+bias, fused Q/K row-L2-norm, V written transposed),
//      1=Wo(+bias+resid fp32), 2=FFN1 gelu->bf16, 3=FFN2(+bias+resid fp32)
// ---------------------------------------------------------------------------
template<int EPI, int K, int BM, int BN, int WR, int WC>
__global__ __launch_bounds__(256)
void gemm_bt(const bf16* __restrict__ A, const bf16* __restrict__ Bt,
             const float* __restrict__ bias0, const float* __restrict__ bias1,
             const float* __restrict__ bias2, const float* __restrict__ resid,
             float* __restrict__ outf, bf16* __restrict__ outb,
             bf16* __restrict__ qo, bf16* __restrict__ ko, bf16* __restrict__ vo) {
    constexpr int MR = BM / WR / 16;   // 16x16 frag repeats per wave (M)
    constexpr int NR = BN / WC / 16;   // 16x16 frag repeats per wave (N)
    constexpr int SA = BM / 32;        // staging iters (8 rows each) for A
    constexpr int SB = BN / 32;
    __shared__ __align__(16) bf16 Al[BM * 64];
    __shared__ __align__(16) bf16 Bl[BN * 64];
    const int tid  = threadIdx.x;
    const int lane = tid & 63, w = tid >> 6;
    const int wr = w / WC, wc = w % WC;
    const int m0 = blockIdx.y * BM, n0 = blockIdx.x * BN;
    const int g = lane >> 4, q = lane & 15;
    const int l3 = lane >> 3, j8 = lane & 7;          // staging coords

    f32x4 acc[MR][NR] = {};
    bf16x8 rA[SA], rB[SB];

    const bf16* ga = A  + (long)(m0 + w * (BM / 4) + l3) * K + j8 * 8;
    const bf16* gb = Bt + (long)(n0 + w * (BN / 4) + l3) * K + j8 * 8;

    auto loadregs = [&](int kt) {
#pragma unroll
        for (int i = 0; i < SA; i++) rA[i] = *(const bf16x8*)(ga + kt + (long)i * 8 * K);
#pragma unroll
        for (int i = 0; i < SB; i++) rB[i] = *(const bf16x8*)(gb + kt + (long)i * 8 * K);
    };
    // frag-major LDS offset (elements) for element (rl, k = j8*8)
    auto ldsoff = [&](int rl) {
        return ((rl >> 4) * 2 + (j8 >> 2)) * 512 + ((j8 & 3) * 16 + (rl & 15)) * 8;
    };
    auto stage = [&]() {
#pragma unroll
        for (int i = 0; i < SA; i++) {
            const int rl = w * (BM / 4) + i * 8 + l3;
            *(bf16x8*)&Al[ldsoff(rl)] = rA[i];
        }
#pragma unroll
        for (int i = 0; i < SB; i++) {
            const int rl = w * (BN / 4) + i * 8 + l3;
            *(bf16x8*)&Bl[ldsoff(rl)] = rB[i];
        }
    };

    loadregs(0);
    for (int kt = 0; kt < K; kt += 64) {
        __syncthreads();                 // prev compute done reading LDS
        stage();
        if (kt + 64 < K) loadregs(kt + 64);   // in flight under compute
        __syncthreads();                 // LDS tile ready
#pragma unroll
        for (int c = 0; c < 2; c++) {
            bf16x8 af[MR], bfr[NR];
#pragma unroll
            for (int i = 0; i < MR; i++)
                af[i] = *(const bf16x8*)&Al[((wr * (BM / WR) >> 4) + i) * 1024 + c * 512 + lane * 8];
#pragma unroll
            for (int i = 0; i < NR; i++)
                bfr[i] = *(const bf16x8*)&Bl[((wc * (BN / WC) >> 4) + i) * 1024 + c * 512 + lane * 8];
#pragma unroll
            for (int mi = 0; mi < MR; mi++)
#pragma unroll
                for (int ni = 0; ni < NR; ni++)
                    acc[mi][ni] = mfma16(af[mi], bfr[ni], acc[mi][ni]);
        }
    }

    // epilogue: C/D frag layout col = lane&15, row = (lane>>4)*4 + r
#pragma unroll
    for (int mi = 0; mi < MR; mi++) {
        if (EPI == 0) {
            // one wave spans exactly one head's 64 cols (n0%128==0, WC=2)
            const int col0  = n0 + wc * 64;
            const int which = (col0 >= 1536) ? 2 : (col0 >= 768 ? 1 : 0);
            const int row0  = m0 + wr * 64 + mi * 16 + g * 4;
            float val[NR][4];
#pragma unroll
            for (int ni = 0; ni < NR; ni++) {
                const int dd = col0 + ni * 16 + q - which * 768;
                const float bias = (which == 0 ? bias0 : which == 1 ? bias1 : bias2)[dd];
#pragma unroll
                for (int r = 0; r < 4; r++) val[ni][r] = acc[mi][ni][r] + bias;
            }
            if (which <= 1) {   // fused per-row L2 norm over the head's 64 dims
#pragma unroll
                for (int r = 0; r < 4; r++) {
                    float ss = val[0][r] * val[0][r];
#pragma unroll
                    for (int ni = 1; ni < NR; ni++) ss += val[ni][r] * val[ni][r];
                    ss += __shfl_xor(ss, 1);
                    ss += __shfl_xor(ss, 2);
                    ss += __shfl_xor(ss, 4);
                    ss += __shfl_xor(ss, 8);
                    const float rn = 1.0f / fmaxf(sqrtf(ss), 1e-12f);
#pragma unroll
                    for (int ni = 0; ni < NR; ni++) val[ni][r] *= rn;
                }
            }
            const int dd0 = col0 - which * 768;
            const int hh  = dd0 >> 6;
            const long bh = (long)(row0 >> 11) * 12 + hh;
#pragma unroll
            for (int ni = 0; ni < NR; ni++) {
                const int dk = ni * 16 + q;
                if (which == 2) {
                    bf16x4 pv;
#pragma unroll
                    for (int r = 0; r < 4; r++) pv[r] = (bf16)val[ni][r];
                    *(bf16x4*)&vo[(bh * 64 + dk) * 2048 + (row0 & 2047)] = pv;
                } else {
                    bf16* dst = (which == 0) ? qo : ko;
#pragma unroll
                    for (int r = 0; r < 4; r++)
                        dst[(bh * 2048 + ((row0 + r) & 2047)) * 64 + dk] = (bf16)val[ni][r];
                }
            }
        } else {
#pragma unroll
            for (int ni = 0; ni < NR; ni++) {
                const int col  = n0 + wc * (BN / WC) + ni * 16 + q;
                const int row0 = m0 + wr * (BM / WR) + mi * 16 + g * 4;
                const float bias = bias0[col];
                if (EPI == 1 || EPI == 3) {
#pragma unroll
                    for (int r = 0; r < 4; r++) {
                        const int row = row0 + r;
                        outf[(long)row * 768 + col] =
                            acc[mi][ni][r] + bias + resid[(long)row * 768 + col];
                    }
                } else { // EPI == 2: exact GELU -> bf16
#pragma unroll
                    for (int r = 0; r < 4; r++) {
                        const float v  = acc[mi][ni][r] + bias;
                        const float gl = 0.5f * v * (1.0f + erff(v * 0.70710678118654752f));
                        outb[(long)(row0 + r) * 3072 + col] = (bf16)gl;
                    }
                }
            }
        }
    }
}

// ---------------------------------------------------------------------------
// Attention (no softmax): O = (Qn Kn^T)^2 @ V  per (b,h).
// Block = 4 waves x 16 q-rows = 64 q-rows; 64-key tiles.
// K/Vt tiles staged cooperatively into double-buffered padded LDS, coalesced
// b128 loads, one barrier per tile, two named register staging sets (A/B),
// loop unrolled x2 (compile-time reg indices, rule #20).
// Swapped QK^T (mfma(K,Q)) -> P written k-contiguous into wave-private
// padded P, re-read as PV A-fragment.
// ---------------------------------------------------------------------------
__global__ __launch_bounds__(256, 2)
void attn_kernel(const bf16* __restrict__ Qn, const bf16* __restrict__ Kn,
                 const bf16* __restrict__ Vt, bf16* __restrict__ AO) {
    const int bh  = blockIdx.y;
    const int tid = threadIdx.x, lane = tid & 63, w = tid >> 6;
    const int g = lane >> 4, q15 = lane & 15;
    const int qbase = blockIdx.x * 64 + w * 16;

    __shared__ __align__(16) bf16 Kl[2][64][72];
    __shared__ __align__(16) bf16 Vl[2][64][72];
    __shared__ __align__(16) bf16 Pl[4][16][72];
    bf16 (*Pw)[72] = Pl[w];

    const bf16* Qp = Qn + (long)bh * S_ * 64;
    const bf16* Kp = Kn + (long)bh * S_ * 64;
    const bf16* Vp = Vt + (long)bh * 64 * S_;

    const int srow = tid >> 3, scol = (tid & 7) * 8;   // staging coords

    bf16x8 qf0 = *(const bf16x8*)&Qp[(long)(qbase + q15) * 64 + g * 8];
    bf16x8 qf1 = *(const bf16x8*)&Qp[(long)(qbase + q15) * 64 + 32 + g * 8];

    f32x4 o[4] = {};

    bf16x8 aK0, aK1, aV0, aV1, bK0, bK1, bV0, bV1;
    auto gloadA = [&](int kt) {
        aK0 = *(const bf16x8*)&Kp[(long)(kt + srow) * 64 + scol];
        aK1 = *(const bf16x8*)&Kp[(long)(kt + 32 + srow) * 64 + scol];
        aV0 = *(const bf16x8*)&Vp[(long)srow * S_ + kt + scol];
        aV1 = *(const bf16x8*)&Vp[(long)(32 + srow) * S_ + kt + scol];
    };
    auto gloadB = [&](int kt) {
        bK0 = *(const bf16x8*)&Kp[(long)(kt + srow) * 64 + scol];
        bK1 = *(const bf16x8*)&Kp[(long)(kt + 32 + srow) * 64 + scol];
        bV0 = *(const bf16x8*)&Vp[(long)srow * S_ + kt + scol];
        bV1 = *(const bf16x8*)&Vp[(long)(32 + srow) * S_ + kt + scol];
    };
    auto stageA = [&](int buf) {
        *(bf16x8*)&Kl[buf][srow][scol]      = aK0;
        *(bf16x8*)&Kl[buf][32 + srow][scol] = aK1;
        *(bf16x8*)&Vl[buf][srow][scol]      = aV0;
        *(bf16x8*)&Vl[buf][32 + srow][scol] = aV1;
    };
    auto stageB = [&](int buf) {
        *(bf16x8*)&Kl[buf][srow][scol]      = bK0;
        *(bf16x8*)&Kl[buf][32 + srow][scol] = bK1;
        *(bf16x8*)&Vl[buf][srow][scol]      = bV0;
        *(bf16x8*)&Vl[buf][32 + srow][scol] = bV1;
    };

    auto compute = [&](int cur) {
        bf16x8 kf[4][2];
#pragma unroll
        for (int ni = 0; ni < 4; ni++)
#pragma unroll
            for (int c = 0; c < 2; c++)
                kf[ni][c] = *(const bf16x8*)&Kl[cur][ni * 16 + q15][c * 32 + g * 8];
        f32x4 s[4];
#pragma unroll
        for (int ni = 0; ni < 4; ni++) {
            s[ni] = mfma16(kf[ni][0], qf0, f32x4{0.f, 0.f, 0.f, 0.f});
            s[ni] = mfma16(kf[ni][1], qf1, s[ni]);
        }
#pragma unroll
        for (int ni = 0; ni < 4; ni++) {
            bf16x4 p4;
#pragma unroll
            for (int r = 0; r < 4; r++) { float v = s[ni][r]; p4[r] = (bf16)(v * v); }
            *(bf16x4*)&Pw[q15][ni * 16 + g * 4] = p4;
        }
        bf16x8 pf0 = *(const bf16x8*)&Pw[q15][g * 8];
        bf16x8 pf1 = *(const bf16x8*)&Pw[q15][32 + g * 8];
        bf16x8 vf[4][2];
#pragma unroll
        for (int ni = 0; ni < 4; ni++)
#pragma unroll
            for (int c = 0; c < 2; c++)
                vf[ni][c] = *(const bf16x8*)&Vl[cur][ni * 16 + q15][c * 32 + g * 8];
#pragma unroll
        for (int ni = 0; ni < 4; ni++) {
            o[ni] = mfma16(pf0, vf[ni][0], o[ni]);
            o[ni] = mfma16(pf1, vf[ni][1], o[ni]);
        }
    };

    gloadA(0);
    stageA(0);
    gloadB(64);
    __syncthreads();
    for (int t = 0; t <= 28; t += 2) {
        stageB(1);
        gloadA((t + 2) * 64);
        compute(0);
        __syncthreads();
        stageA(0);
        if (t + 3 < 32) gloadB((t + 3) * 64);
        compute(1);
        __syncthreads();
    }
    stageB(1);
    compute(0);
    __syncthreads();
    compute(1);

    const int b = bh / 12, h = bh % 12;
#pragma unroll
    for (int ni = 0; ni < 4; ni++)
#pragma unroll
        for (int r = 0; r < 4; r++) {
            const int s = qbase + g * 4 + r;
            AO[((long)b * S_ + s) * D_ + h * 64 + ni * 16 + q15] = (bf16)o[ni][r];
        }
}

// ---------------------------------------------------------------------------
// LayerNorm over D=768. One block per row, 256 threads (3 elems each).
// ---------------------------------------------------------------------------
template<bool WB>
__global__ __launch_bounds__(256)
void ln_kernel(const float* __restrict__ y, const float* __restrict__ gamma,
               const float* __restrict__ beta, float* __restrict__ xo,
               bf16* __restrict__ xob) {
    __shared__ float sa[4], sb[4];
    const int row = blockIdx.x, t = threadIdx.x;
    const float* yr = y + (long)row * 768;
    float v0 = yr[t], v1 = yr[t + 256], v2 = yr[t + 512];
    float s  = v0 + v1 + v2;
    float ss = v0 * v0 + v1 * v1 + v2 * v2;
#pragma unroll
    for (int o = 32; o; o >>= 1) { s += __shfl_xor(s, o); ss += __shfl_xor(ss, o); }
    if ((t & 63) == 0) { sa[t >> 6] = s; sb[t >> 6] = ss; }
    __syncthreads();
    s  = sa[0] + sa[1] + sa[2] + sa[3];
    ss = sb[0] + sb[1] + sb[2] + sb[3];
    const float mu   = s * (1.0f / 768.0f);
    const float var  = ss * (1.0f / 768.0f) - mu * mu;
    const float rstd = rsqrtf(var + 1e-5f);
    float* xr = xo + (long)row * 768;
#pragma unroll
    for (int i = 0; i < 3; i++) {
        const int c = t + i * 256;
        const float vv = (i == 0) ? v0 : (i == 1) ? v1 : v2;
        const float ov = (vv - mu) * rstd * gamma[c] + beta[c];
        xr[c] = ov;
        if (WB) xob[(long)row * 768 + c] = (bf16)ov;
    }
}

// ---------------------------------------------------------------------------
extern "C" void kernel_launch(void* const* d_in, const int* in_sizes, int n_in,
                              void* d_out, int out_size, void* d_ws, size_t ws_size,
                              hipStream_t stream) {
    const float* x     = (const float*)d_in[0];
    const float* Wq    = (const float*)d_in[1];
    const float* bq    = (const float*)d_in[2];
    const float* Wk    = (const float*)d_in[3];
    const float* bk    = (const float*)d_in[4];
    const float* Wv    = (const float*)d_in[5];
    const float* bv    = (const float*)d_in[6];
    const float* Wo    = (const float*)d_in[7];
    const float* bo    = (const float*)d_in[8];
    const float* W1    = (const float*)d_in[9];
    const float* b1    = (const float*)d_in[10];
    const float* W2    = (const float*)d_in[11];
    const float* b2    = (const float*)d_in[12];
    const float* gamma = (const float*)d_in[13];
    const float* beta  = (const float*)d_in[14];

    char* p = (char*)d_ws;
    auto alloc = [&](size_t bytes) -> void* {
        void* r = p;
        p += (bytes + 255) & ~(size_t)255;
        return r;
    };
    bf16*  Xb    = (bf16*)alloc((size_t)M_ * D_ * 2);
    bf16*  Wqkvt = (bf16*)alloc((size_t)2304 * 768 * 2);
    bf16*  Wot   = (bf16*)alloc((size_t)768 * 768 * 2);
    bf16*  W1t   = (bf16*)alloc((size_t)3072 * 768 * 2);
    bf16*  W2t   = (bf16*)alloc((size_t)768 * 3072 * 2);
    bf16*  Qh    = (bf16*)alloc((size_t)BH_ * S_ * 64 * 2);
    bf16*  Kh    = (bf16*)alloc((size_t)BH_ * S_ * 64 * 2);
    bf16*  Vt    = (bf16*)alloc((size_t)BH_ * S_ * 64 * 2);
    bf16*  AO    = (bf16*)alloc((size_t)M_ * D_ * 2);
    float* y1    = (float*)alloc((size_t)M_ * D_ * 4);
    float* x1    = (float*)alloc((size_t)M_ * D_ * 4);
    bf16*  x1b   = (bf16*)alloc((size_t)M_ * D_ * 2);
    bf16*  hbuf  = (bf16*)alloc((size_t)M_ * DFF_ * 2);
    float* y2    = y1;  // y1 dead after LN1

    // pack + transpose weights (one launch)
    pack_x_kernel<<<(M_ * D_) / 1024, 256, 0, stream>>>(x, Xb);
    wt_all_kernel<<<1728, 256, 0, stream>>>(Wq, Wk, Wv, Wo, W1, W2,
                                            Wqkvt, Wot, W1t, W2t);

    // QKV projection (+fused Q/K L2-norm) -> Qh/Kh [bh][s][dk], Vt [bh][dk][s]
    gemm_bt<0, 768, 128, 128, 2, 2><<<dim3(18, 32), 256, 0, stream>>>(
        Xb, Wqkvt, bq, bk, bv, nullptr, nullptr, nullptr, Qh, Kh, Vt);

    // attention
    attn_kernel<<<dim3(S_ / 64, BH_), 256, 0, stream>>>(Qh, Kh, Vt, AO);

    // out projection + residual, LN1  (64x128 tiles -> 384 blocks)
    gemm_bt<1, 768, 64, 128, 1, 4><<<dim3(6, 64), 256, 0, stream>>>(
        AO, Wot, bo, nullptr, nullptr, x, y1, nullptr, nullptr, nullptr, nullptr);
    ln_kernel<true><<<M_, 256, 0, stream>>>(y1, gamma, beta, x1, x1b);

    // FFN
    gemm_bt<2, 768, 128, 128, 2, 2><<<dim3(24, 32), 256, 0, stream>>>(
        x1b, W1t, b1, nullptr, nullptr, nullptr, nullptr, hbuf, nullptr, nullptr, nullptr);
    gemm_bt<3, 3072, 64, 128, 1, 4><<<dim3(6, 64), 256, 0, stream>>>(
        hbuf, W2t, b2, nullptr, nullptr, x1, y2, nullptr, nullptr, nullptr, nullptr);
    ln_kernel<false><<<M_, 256, 0, stream>>>(y2, gamma, beta, (float*)d_out, nullptr);
}

// Round 6
// 248.338 us; speedup vs baseline: 1.1285x; 1.1285x over previous
//
#include <hip/hip_runtime.h>
#include <math.h>

// ---------------------------------------------------------------------------
// EncoderLayer: B=2,S=2048,D=768,H=12,DK=64,DFF=3072
// bf16 MFMA (16x16x32) for all matmuls, fp32 accumulate + fp32 pointwise.
// ---------------------------------------------------------------------------

using bf16   = __bf16;
using bf16x8 = __attribute__((ext_vector_type(8))) __bf16;
using bf16x4 = __attribute__((ext_vector_type(4))) __bf16;
using f32x4  = __attribute__((ext_vector_type(4))) float;

constexpr int S_   = 2048;
constexpr int D_   = 768;
constexpr int DFF_ = 3072;
constexpr int M_   = 4096;   // B*S
constexpr int BH_  = 24;     // B*H

__device__ __forceinline__ f32x4 mfma16(bf16x8 a, bf16x8 b, f32x4 c) {
    return __builtin_amdgcn_mfma_f32_16x16x32_bf16(a, b, c, 0, 0, 0);
}

// async global->LDS, 16B per lane; LDS dest wave-uniform, lane fills base+l*16
__device__ __forceinline__ void gload16(const bf16* g, bf16* l) {
    __builtin_amdgcn_global_load_lds(
        (const __attribute__((address_space(1))) void*)g,
        (__attribute__((address_space(3))) void*)l, 16, 0, 0);
}

// ---------------------------------------------------------------------------
// pack x (fp32 -> bf16), 4 elems/thread
// ---------------------------------------------------------------------------
__global__ __launch_bounds__(256)
void pack_x_kernel(const float* __restrict__ x, bf16* __restrict__ xb) {
    const int i = blockIdx.x * 256 + threadIdx.x;
    float4 v = ((const float4*)x)[i];
    bf16x4 o;
    o[0] = (bf16)v.x; o[1] = (bf16)v.y; o[2] = (bf16)v.z; o[3] = (bf16)v.w;
    ((bf16x4*)xb)[i] = o;
}

// ---------------------------------------------------------------------------
// ALL weight transposes in one launch: in [K][N] fp32 -> out [N][K] bf16.
// 64x64 tiles, flat block index -> (matrix, tile).
// ---------------------------------------------------------------------------
__global__ __launch_bounds__(256)
void wt_all_kernel(const float* __restrict__ Wq, const float* __restrict__ Wk,
                   const float* __restrict__ Wv, const float* __restrict__ Wo,
                   const float* __restrict__ W1, const float* __restrict__ W2,
                   bf16* __restrict__ Wqkvt, bf16* __restrict__ Wot,
                   bf16* __restrict__ W1t, bf16* __restrict__ W2t) {
    int bid = blockIdx.x;
    const float* in; bf16* out; int K, N, t;
    if (bid < 576) {                       // Wq/Wk/Wv/Wo: 144 tiles each
        int m = bid / 144; t = bid % 144; K = 768; N = 768;
        in  = (m == 0) ? Wq : (m == 1) ? Wk : (m == 2) ? Wv : Wo;
        out = (m == 3) ? Wot : Wqkvt + (size_t)m * 768 * 768;
    } else if (bid < 1152) {               // W1: [768][3072] -> [3072][768]
        t = bid - 576; K = 768; N = 3072; in = W1; out = W1t;
    } else {                               // W2: [3072][768] -> [768][3072]
        t = bid - 1152; K = 3072; N = 768; in = W2; out = W2t;
    }
    const int ntx = N / 64;
    const int n0 = (t % ntx) * 64, k0 = (t / ntx) * 64;

    __shared__ __align__(16) bf16 T[64][72];
    const int tt = threadIdx.x;
    const int r  = tt >> 2, c0 = (tt & 3) * 16;
    const float* src = in + (size_t)(k0 + r) * N + n0 + c0;
#pragma unroll
    for (int j = 0; j < 16; j += 4) {
        float4 v = *(const float4*)(src + j);
        T[r][c0 + j + 0] = (bf16)v.x;
        T[r][c0 + j + 1] = (bf16)v.y;
        T[r][c0 + j + 2] = (bf16)v.z;
        T[r][c0 + j + 3] = (bf16)v.w;
    }
    __syncthreads();
    bf16x8 o0, o1;
#pragma unroll
    for (int j = 0; j < 8; j++) { o0[j] = T[c0 + j][r]; o1[j] = T[c0 + 8 + j][r]; }
    bf16* dst = out + (size_t)(n0 + r) * K + k0 + c0;
    *(bf16x8*)(dst)     = o0;
    *(bf16x8*)(dst + 8) = o1;
}

// ---------------------------------------------------------------------------
// GEMM: C = A[M,K] @ Bt[N,K]^T, BMxBN tile, BK=64, 4 waves in WRxWC grid.
// Staging: global_load_lds (async, 16B) with PRE-SWIZZLED GLOBAL SOURCE so
// the linear HW write order (base + lane*16B) lands the tile in FRAGMENT-
// MAJOR layout: one gload16 = one 1KB MFMA fragment; lane l loads element
// (row = rblk*16 + (l&15), k = c*32 + (l>>4)*8). Fragment reads are then
// frag*1024B + lane*16B -> ZERO bank conflicts, both sides (rule #21).
// EPI: 0=QKV (+bias, fused Q/K row-L2-norm, V written transposed),
//      1=Wo(+bias+fp32 resid)->bf16, 2=FFN1 gelu->bf16,
//      3=FFN2(+bias+bf16 resid)->bf16
// ---------------------------------------------------------------------------
template<int EPI, int K, int BM, int BN, int WR, int WC>
__global__ __launch_bounds__(256)
void gemm_bt(const bf16* __restrict__ A, const bf16* __restrict__ Bt,
             const float* __restrict__ bias0, const float* __restrict__ bias1,
             const float* __restrict__ bias2, const float* __restrict__ residf,
             const bf16* __restrict__ residb, bf16* __restrict__ outb,
             bf16* __restrict__ qo, bf16* __restrict__ ko, bf16* __restrict__ vo) {
    constexpr int MR = BM / WR / 16;   // 16x16 frag repeats per wave (M)
    constexpr int NR = BN / WC / 16;   // 16x16 frag repeats per wave (N)
    constexpr int FA = (BM / 16) * 2;  // 1KB fragments per K-tile of A
    constexpr int FB = (BN / 16) * 2;
    __shared__ __align__(16) bf16 Al[FA * 512];
    __shared__ __align__(16) bf16 Bl[FB * 512];
    const int tid  = threadIdx.x;
    const int lane = tid & 63, w = tid >> 6;
    const int wr = w / WC, wc = w % WC;
    const int m0 = blockIdx.y * BM, n0 = blockIdx.x * BN;
    const int g = lane >> 4, q = lane & 15;

    f32x4 acc[MR][NR] = {};

    // per-lane swizzled global base: row += q, col += g*8
    const bf16* gaA = A  + (long)(m0 + q) * K + g * 8;
    const bf16* gaB = Bt + (long)(n0 + q) * K + g * 8;

    for (int kt = 0; kt < K; kt += 64) {
        __syncthreads();                 // prev compute done reading LDS
#pragma unroll
        for (int fi = 0; fi < FA; fi++)
            if ((fi & 3) == w)
                gload16(gaA + (long)(fi >> 1) * 16 * K + kt + (fi & 1) * 32,
                        &Al[fi * 512]);
#pragma unroll
        for (int fi = 0; fi < FB; fi++)
            if ((fi & 3) == w)
                gload16(gaB + (long)(fi >> 1) * 16 * K + kt + (fi & 1) * 32,
                        &Bl[fi * 512]);
        __syncthreads();                 // (compiler drains vmcnt before barrier)
#pragma unroll
        for (int c = 0; c < 2; c++) {
            bf16x8 af[MR], bfr[NR];
#pragma unroll
            for (int i = 0; i < MR; i++)
                af[i] = *(const bf16x8*)&Al[((((wr * (BM / WR)) >> 4) + i) * 2 + c) * 512 + lane * 8];
#pragma unroll
            for (int i = 0; i < NR; i++)
                bfr[i] = *(const bf16x8*)&Bl[((((wc * (BN / WC)) >> 4) + i) * 2 + c) * 512 + lane * 8];
#pragma unroll
            for (int mi = 0; mi < MR; mi++)
#pragma unroll
                for (int ni = 0; ni < NR; ni++)
                    acc[mi][ni] = mfma16(af[mi], bfr[ni], acc[mi][ni]);
        }
    }

    // epilogue: C/D frag layout col = lane&15, row = (lane>>4)*4 + r
#pragma unroll
    for (int mi = 0; mi < MR; mi++) {
        if (EPI == 0) {
            // one wave spans exactly one head's 64 cols (BN/WC == 64)
            const int col0  = n0 + wc * 64;
            const int which = (col0 >= 1536) ? 2 : (col0 >= 768 ? 1 : 0);
            const int row0  = m0 + wr * (BM / WR) + mi * 16 + g * 4;
            float val[NR][4];
#pragma unroll
            for (int ni = 0; ni < NR; ni++) {
                const int dd = col0 + ni * 16 + q - which * 768;
                const float bias = (which == 0 ? bias0 : which == 1 ? bias1 : bias2)[dd];
#pragma unroll
                for (int r = 0; r < 4; r++) val[ni][r] = acc[mi][ni][r] + bias;
            }
            if (which <= 1) {   // fused per-row L2 norm over the head's 64 dims
#pragma unroll
                for (int r = 0; r < 4; r++) {
                    float ss = val[0][r] * val[0][r];
#pragma unroll
                    for (int ni = 1; ni < NR; ni++) ss += val[ni][r] * val[ni][r];
                    ss += __shfl_xor(ss, 1);
                    ss += __shfl_xor(ss, 2);
                    ss += __shfl_xor(ss, 4);
                    ss += __shfl_xor(ss, 8);
                    const float rn = 1.0f / fmaxf(sqrtf(ss), 1e-12f);
#pragma unroll
                    for (int ni = 0; ni < NR; ni++) val[ni][r] *= rn;
                }
            }
            const int dd0 = col0 - which * 768;
            const int hh  = dd0 >> 6;
            const long bh = (long)(row0 >> 11) * 12 + hh;
#pragma unroll
            for (int ni = 0; ni < NR; ni++) {
                const int dk = ni * 16 + q;
                if (which == 2) {
                    bf16x4 pv;
#pragma unroll
                    for (int r = 0; r < 4; r++) pv[r] = (bf16)val[ni][r];
                    *(bf16x4*)&vo[(bh * 64 + dk) * 2048 + (row0 & 2047)] = pv;
                } else {
                    bf16* dst = (which == 0) ? qo : ko;
#pragma unroll
                    for (int r = 0; r < 4; r++)
                        dst[(bh * 2048 + ((row0 + r) & 2047)) * 64 + dk] = (bf16)val[ni][r];
                }
            }
        } else {
#pragma unroll
            for (int ni = 0; ni < NR; ni++) {
                const int col  = n0 + wc * (BN / WC) + ni * 16 + q;
                const int row0 = m0 + wr * (BM / WR) + mi * 16 + g * 4;
                const float bias = bias0[col];
                if (EPI == 1) {          // + fp32 residual -> bf16
#pragma unroll
                    for (int r = 0; r < 4; r++) {
                        const int row = row0 + r;
                        outb[(long)row * 768 + col] =
                            (bf16)(acc[mi][ni][r] + bias + residf[(long)row * 768 + col]);
                    }
                } else if (EPI == 3) {   // + bf16 residual -> bf16
#pragma unroll
                    for (int r = 0; r < 4; r++) {
                        const int row = row0 + r;
                        outb[(long)row * 768 + col] =
                            (bf16)(acc[mi][ni][r] + bias + (float)residb[(long)row * 768 + col]);
                    }
                } else {                 // EPI == 2: exact GELU -> bf16
#pragma unroll
                    for (int r = 0; r < 4; r++) {
                        const float v  = acc[mi][ni][r] + bias;
                        const float gl = 0.5f * v * (1.0f + erff(v * 0.70710678118654752f));
                        outb[(long)(row0 + r) * 3072 + col] = (bf16)gl;
                    }
                }
            }
        }
    }
}

// ---------------------------------------------------------------------------
// Attention (no softmax): O = (Qn Kn^T)^2 @ V  per (b,h).
// Block = 4 waves x 16 q-rows = 64 q-rows; 64-key tiles.
// K/Vt tiles staged cooperatively into double-buffered padded LDS, coalesced
// b128 loads, one barrier per tile, two named register staging sets (A/B),
// loop unrolled x2 (compile-time reg indices, rule #20).
// Swapped QK^T (mfma(K,Q)) -> P written k-contiguous into wave-private
// padded P, re-read as PV A-fragment.
// ---------------------------------------------------------------------------
__global__ __launch_bounds__(256, 2)
void attn_kernel(const bf16* __restrict__ Qn, const bf16* __restrict__ Kn,
                 const bf16* __restrict__ Vt, bf16* __restrict__ AO) {
    const int bh  = blockIdx.y;
    const int tid = threadIdx.x, lane = tid & 63, w = tid >> 6;
    const int g = lane >> 4, q15 = lane & 15;
    const int qbase = blockIdx.x * 64 + w * 16;

    __shared__ __align__(16) bf16 Kl[2][64][72];
    __shared__ __align__(16) bf16 Vl[2][64][72];
    __shared__ __align__(16) bf16 Pl[4][16][72];
    bf16 (*Pw)[72] = Pl[w];

    const bf16* Qp = Qn + (long)bh * S_ * 64;
    const bf16* Kp = Kn + (long)bh * S_ * 64;
    const bf16* Vp = Vt + (long)bh * 64 * S_;

    const int srow = tid >> 3, scol = (tid & 7) * 8;   // staging coords

    bf16x8 qf0 = *(const bf16x8*)&Qp[(long)(qbase + q15) * 64 + g * 8];
    bf16x8 qf1 = *(const bf16x8*)&Qp[(long)(qbase + q15) * 64 + 32 + g * 8];

    f32x4 o[4] = {};

    bf16x8 aK0, aK1, aV0, aV1, bK0, bK1, bV0, bV1;
    auto gloadA = [&](int kt) {
        aK0 = *(const bf16x8*)&Kp[(long)(kt + srow) * 64 + scol];
        aK1 = *(const bf16x8*)&Kp[(long)(kt + 32 + srow) * 64 + scol];
        aV0 = *(const bf16x8*)&Vp[(long)srow * S_ + kt + scol];
        aV1 = *(const bf16x8*)&Vp[(long)(32 + srow) * S_ + kt + scol];
    };
    auto gloadB = [&](int kt) {
        bK0 = *(const bf16x8*)&Kp[(long)(kt + srow) * 64 + scol];
        bK1 = *(const bf16x8*)&Kp[(long)(kt + 32 + srow) * 64 + scol];
        bV0 = *(const bf16x8*)&Vp[(long)srow * S_ + kt + scol];
        bV1 = *(const bf16x8*)&Vp[(long)(32 + srow) * S_ + kt + scol];
    };
    auto stageA = [&](int buf) {
        *(bf16x8*)&Kl[buf][srow][scol]      = aK0;
        *(bf16x8*)&Kl[buf][32 + srow][scol] = aK1;
        *(bf16x8*)&Vl[buf][srow][scol]      = aV0;
        *(bf16x8*)&Vl[buf][32 + srow][scol] = aV1;
    };
    auto stageB = [&](int buf) {
        *(bf16x8*)&Kl[buf][srow][scol]      = bK0;
        *(bf16x8*)&Kl[buf][32 + srow][scol] = bK1;
        *(bf16x8*)&Vl[buf][srow][scol]      = bV0;
        *(bf16x8*)&Vl[buf][32 + srow][scol] = bV1;
    };

    auto compute = [&](int cur) {
        bf16x8 kf[4][2];
#pragma unroll
        for (int ni = 0; ni < 4; ni++)
#pragma unroll
            for (int c = 0; c < 2; c++)
                kf[ni][c] = *(const bf16x8*)&Kl[cur][ni * 16 + q15][c * 32 + g * 8];
        f32x4 s[4];
#pragma unroll
        for (int ni = 0; ni < 4; ni++) {
            s[ni] = mfma16(kf[ni][0], qf0, f32x4{0.f, 0.f, 0.f, 0.f});
            s[ni] = mfma16(kf[ni][1], qf1, s[ni]);
        }
#pragma unroll
        for (int ni = 0; ni < 4; ni++) {
            bf16x4 p4;
#pragma unroll
            for (int r = 0; r < 4; r++) { float v = s[ni][r]; p4[r] = (bf16)(v * v); }
            *(bf16x4*)&Pw[q15][ni * 16 + g * 4] = p4;
        }
        bf16x8 pf0 = *(const bf16x8*)&Pw[q15][g * 8];
        bf16x8 pf1 = *(const bf16x8*)&Pw[q15][32 + g * 8];
        bf16x8 vf[4][2];
#pragma unroll
        for (int ni = 0; ni < 4; ni++)
#pragma unroll
            for (int c = 0; c < 2; c++)
                vf[ni][c] = *(const bf16x8*)&Vl[cur][ni * 16 + q15][c * 32 + g * 8];
#pragma unroll
        for (int ni = 0; ni < 4; ni++) {
            o[ni] = mfma16(pf0, vf[ni][0], o[ni]);
            o[ni] = mfma16(pf1, vf[ni][1], o[ni]);
        }
    };

    gloadA(0);
    stageA(0);
    gloadB(64);
    __syncthreads();
    for (int t = 0; t <= 28; t += 2) {
        stageB(1);
        gloadA((t + 2) * 64);
        compute(0);
        __syncthreads();
        stageA(0);
        if (t + 3 < 32) gloadB((t + 3) * 64);
        compute(1);
        __syncthreads();
    }
    stageB(1);
    compute(0);
    __syncthreads();
    compute(1);

    const int b = bh / 12, h = bh % 12;
#pragma unroll
    for (int ni = 0; ni < 4; ni++)
#pragma unroll
        for (int r = 0; r < 4; r++) {
            const int s = qbase + g * 4 + r;
            AO[((long)b * S_ + s) * D_ + h * 64 + ni * 16 + q15] = (bf16)o[ni][r];
        }
}

// ---------------------------------------------------------------------------
// LayerNorm over D=768 (bf16 input). One block per row, 256 threads.
// WB=true: write bf16 only (mid-layer). WB=false: write fp32 (final out).
// ---------------------------------------------------------------------------
template<bool WB>
__global__ __launch_bounds__(256)
void ln_kernel(const bf16* __restrict__ y, const float* __restrict__ gamma,
               const float* __restrict__ beta, float* __restrict__ xo,
               bf16* __restrict__ xob) {
    __shared__ float sa[4], sb[4];
    const int row = blockIdx.x, t = threadIdx.x;
    const bf16* yr = y + (long)row * 768;
    float v0 = (float)yr[t], v1 = (float)yr[t + 256], v2 = (float)yr[t + 512];
    float s  = v0 + v1 + v2;
    float ss = v0 * v0 + v1 * v1 + v2 * v2;
#pragma unroll
    for (int o = 32; o; o >>= 1) { s += __shfl_xor(s, o); ss += __shfl_xor(ss, o); }
    if ((t & 63) == 0) { sa[t >> 6] = s; sb[t >> 6] = ss; }
    __syncthreads();
    s  = sa[0] + sa[1] + sa[2] + sa[3];
    ss = sb[0] + sb[1] + sb[2] + sb[3];
    const float mu   = s * (1.0f / 768.0f);
    const float var  = ss * (1.0f / 768.0f) - mu * mu;
    const float rstd = rsqrtf(var + 1e-5f);
#pragma unroll
    for (int i = 0; i < 3; i++) {
        const int c = t + i * 256;
        const float vv = (i == 0) ? v0 : (i == 1) ? v1 : v2;
        const float ov = (vv - mu) * rstd * gamma[c] + beta[c];
        if (WB) xob[(long)row * 768 + c] = (bf16)ov;
        else    xo[(long)row * 768 + c] = ov;
    }
}

// ---------------------------------------------------------------------------
extern "C" void kernel_launch(void* const* d_in, const int* in_sizes, int n_in,
                              void* d_out, int out_size, void* d_ws, size_t ws_size,
                              hipStream_t stream) {
    const float* x     = (const float*)d_in[0];
    const float* Wq    = (const float*)d_in[1];
    const float* bq    = (const float*)d_in[2];
    const float* Wk    = (const float*)d_in[3];
    const float* bk    = (const float*)d_in[4];
    const float* Wv    = (const float*)d_in[5];
    const float* bv    = (const float*)d_in[6];
    const float* Wo    = (const float*)d_in[7];
    const float* bo    = (const float*)d_in[8];
    const float* W1    = (const float*)d_in[9];
    const float* b1    = (const float*)d_in[10];
    const float* W2    = (const float*)d_in[11];
    const float* b2    = (const float*)d_in[12];
    const float* gamma = (const float*)d_in[13];
    const float* beta  = (const float*)d_in[14];

    char* p = (char*)d_ws;
    auto alloc = [&](size_t bytes) -> void* {
        void* r = p;
        p += (bytes + 255) & ~(size_t)255;
        return r;
    };
    bf16*  Xb    = (bf16*)alloc((size_t)M_ * D_ * 2);
    bf16*  Wqkvt = (bf16*)alloc((size_t)2304 * 768 * 2);
    bf16*  Wot   = (bf16*)alloc((size_t)768 * 768 * 2);
    bf16*  W1t   = (bf16*)alloc((size_t)3072 * 768 * 2);
    bf16*  W2t   = (bf16*)alloc((size_t)768 * 3072 * 2);
    bf16*  Qh    = (bf16*)alloc((size_t)BH_ * S_ * 64 * 2);
    bf16*  Kh    = (bf16*)alloc((size_t)BH_ * S_ * 64 * 2);
    bf16*  Vt    = (bf16*)alloc((size_t)BH_ * S_ * 64 * 2);
    bf16*  AO    = (bf16*)alloc((size_t)M_ * D_ * 2);
    bf16*  y1b   = (bf16*)alloc((size_t)M_ * D_ * 2);
    bf16*  x1b   = (bf16*)alloc((size_t)M_ * D_ * 2);
    bf16*  hbuf  = (bf16*)alloc((size_t)M_ * DFF_ * 2);
    bf16*  y2b   = y1b;  // y1b dead after LN1

    // pack + transpose weights (one launch)
    pack_x_kernel<<<(M_ * D_) / 1024, 256, 0, stream>>>(x, Xb);
    wt_all_kernel<<<1728, 256, 0, stream>>>(Wq, Wk, Wv, Wo, W1, W2,
                                            Wqkvt, Wot, W1t, W2t);

    // QKV projection (+fused Q/K L2-norm) -> Qh/Kh [bh][s][dk], Vt [bh][dk][s]
    gemm_bt<0, 768, 128, 128, 2, 2><<<dim3(18, 32), 256, 0, stream>>>(
        Xb, Wqkvt, bq, bk, bv, nullptr, nullptr, nullptr, Qh, Kh, Vt);

    // attention
    attn_kernel<<<dim3(S_ / 64, BH_), 256, 0, stream>>>(Qh, Kh, Vt, AO);

    // out projection + residual -> bf16, LN1   (64x64 tiles -> 768 blocks)
    gemm_bt<1, 768, 64, 64, 2, 2><<<dim3(12, 64), 256, 0, stream>>>(
        AO, Wot, bo, nullptr, nullptr, x, nullptr, y1b, nullptr, nullptr, nullptr);
    ln_kernel<true><<<M_, 256, 0, stream>>>(y1b, gamma, beta, nullptr, x1b);

    // FFN
    gemm_bt<2, 768, 128, 128, 2, 2><<<dim3(24, 32), 256, 0, stream>>>(
        x1b, W1t, b1, nullptr, nullptr, nullptr, nullptr, hbuf, nullptr, nullptr, nullptr);
    gemm_bt<3, 3072, 64, 64, 2, 2><<<dim3(12, 64), 256, 0, stream>>>(
        hbuf, W2t, b2, nullptr, nullptr, nullptr, x1b, y2b, nullptr, nullptr, nullptr);
    ln_kernel<false><<<M_, 256, 0, stream>>>(y2b, gamma, beta, (float*)d_out, nullptr);
}

// Round 7
// 247.264 us; speedup vs baseline: 1.1334x; 1.0043x over previous
//
#include <hip/hip_runtime.h>
#include <math.h>

// ---------------------------------------------------------------------------
// EncoderLayer: B=2,S=2048,D=768,H=12,DK=64,DFF=3072
// bf16 MFMA (16x16x32) for all matmuls, fp32 accumulate + fp32 pointwise.
// ---------------------------------------------------------------------------

using bf16   = __bf16;
using bf16x8 = __attribute__((ext_vector_type(8))) __bf16;
using bf16x4 = __attribute__((ext_vector_type(4))) __bf16;
using f32x4  = __attribute__((ext_vector_type(4))) float;

constexpr int S_   = 2048;
constexpr int D_   = 768;
constexpr int DFF_ = 3072;
constexpr int M_   = 4096;   // B*S
constexpr int BH_  = 24;     // B*H

__device__ __forceinline__ f32x4 mfma16(bf16x8 a, bf16x8 b, f32x4 c) {
    return __builtin_amdgcn_mfma_f32_16x16x32_bf16(a, b, c, 0, 0, 0);
}

// async global->LDS, 16B per lane; LDS dest wave-uniform, lane fills base+l*16
__device__ __forceinline__ void gload16(const bf16* g, bf16* l) {
    __builtin_amdgcn_global_load_lds(
        (const __attribute__((address_space(1))) void*)g,
        (__attribute__((address_space(3))) void*)l, 16, 0, 0);
}

// bijective XCD-cluster swizzle; valid when nwg % 8 == 0
__device__ __forceinline__ int xcd_swz(int orig, int nwg) {
    return (orig & 7) * (nwg >> 3) + (orig >> 3);
}

// ---------------------------------------------------------------------------
// pack x (fp32 -> bf16), 4 elems/thread
// ---------------------------------------------------------------------------
__global__ __launch_bounds__(256)
void pack_x_kernel(const float* __restrict__ x, bf16* __restrict__ xb) {
    const int i = blockIdx.x * 256 + threadIdx.x;
    float4 v = ((const float4*)x)[i];
    bf16x4 o;
    o[0] = (bf16)v.x; o[1] = (bf16)v.y; o[2] = (bf16)v.z; o[3] = (bf16)v.w;
    ((bf16x4*)xb)[i] = o;
}

// ---------------------------------------------------------------------------
// ALL weight transposes in one launch: in [K][N] fp32 -> out [N][K] bf16.
// 64x64 tiles, flat block index -> (matrix, tile).
// ---------------------------------------------------------------------------
__global__ __launch_bounds__(256)
void wt_all_kernel(const float* __restrict__ Wq, const float* __restrict__ Wk,
                   const float* __restrict__ Wv, const float* __restrict__ Wo,
                   const float* __restrict__ W1, const float* __restrict__ W2,
                   bf16* __restrict__ Wqkvt, bf16* __restrict__ Wot,
                   bf16* __restrict__ W1t, bf16* __restrict__ W2t) {
    int bid = blockIdx.x;
    const float* in; bf16* out; int K, N, t;
    if (bid < 576) {                       // Wq/Wk/Wv/Wo: 144 tiles each
        int m = bid / 144; t = bid % 144; K = 768; N = 768;
        in  = (m == 0) ? Wq : (m == 1) ? Wk : (m == 2) ? Wv : Wo;
        out = (m == 3) ? Wot : Wqkvt + (size_t)m * 768 * 768;
    } else if (bid < 1152) {               // W1: [768][3072] -> [3072][768]
        t = bid - 576; K = 768; N = 3072; in = W1; out = W1t;
    } else {                               // W2: [3072][768] -> [768][3072]
        t = bid - 1152; K = 3072; N = 768; in = W2; out = W2t;
    }
    const int ntx = N / 64;
    const int n0 = (t % ntx) * 64, k0 = (t / ntx) * 64;

    __shared__ __align__(16) bf16 T[64][72];
    const int tt = threadIdx.x;
    const int r  = tt >> 2, c0 = (tt & 3) * 16;
    const float* src = in + (size_t)(k0 + r) * N + n0 + c0;
#pragma unroll
    for (int j = 0; j < 16; j += 4) {
        float4 v = *(const float4*)(src + j);
        T[r][c0 + j + 0] = (bf16)v.x;
        T[r][c0 + j + 1] = (bf16)v.y;
        T[r][c0 + j + 2] = (bf16)v.z;
        T[r][c0 + j + 3] = (bf16)v.w;
    }
    __syncthreads();
    bf16x8 o0, o1;
#pragma unroll
    for (int j = 0; j < 8; j++) { o0[j] = T[c0 + j][r]; o1[j] = T[c0 + 8 + j][r]; }
    bf16* dst = out + (size_t)(n0 + r) * K + k0 + c0;
    *(bf16x8*)(dst)     = o0;
    *(bf16x8*)(dst + 8) = o1;
}

// ---------------------------------------------------------------------------
// GEMM: C = A[M,K] @ Bt[N,K]^T, BMxBN tile, BK=64, 4 waves in WRxWC grid.
// Staging: global_load_lds (async 16B) with pre-swizzled global source ->
// fragment-major LDS (one gload16 = one 1KB MFMA fragment); fragment reads
// are frag*1024B + lane*16B -> zero bank conflicts both sides.
// DB=true: double-buffered 2-phase pipeline (stage t+1 before compute t,
//          ONE barrier/K-step -> loads fly under compute).  LDS = 2 tiles.
// DB=false: m97 2-barrier single-buffer (for 128^2 where dbuf LDS = 64KB).
// 1D grid + bijective XCD swizzle (same-A-panel blocks share an XCD L2).
// EPI: 0=QKV (+bias, fused Q/K row-L2-norm, V written transposed),
//      1=Wo(+bias+fp32 resid)->bf16, 2=FFN1 gelu->bf16,
//      3=FFN2(+bias+bf16 resid)->bf16
// ---------------------------------------------------------------------------
template<int EPI, int K, int BM, int BN, int WR, int WC, bool DB>
__global__ __launch_bounds__(256)
void gemm_bt(const bf16* __restrict__ A, const bf16* __restrict__ Bt,
             const float* __restrict__ bias0, const float* __restrict__ bias1,
             const float* __restrict__ bias2, const float* __restrict__ residf,
             const bf16* __restrict__ residb, bf16* __restrict__ outb,
             bf16* __restrict__ qo, bf16* __restrict__ ko, bf16* __restrict__ vo) {
    constexpr int MR = BM / WR / 16;
    constexpr int NR = BN / WC / 16;
    constexpr int FA = (BM / 16) * 2;  // 1KB fragments per K-tile of A
    constexpr int FB = (BN / 16) * 2;
    constexpr int NCOL = (EPI == 0) ? 2304 : (EPI == 2) ? 3072 : 768;
    constexpr int NBX  = NCOL / BN;
    __shared__ __align__(16) bf16 Al[(DB ? 2 : 1) * FA * 512];
    __shared__ __align__(16) bf16 Bl[(DB ? 2 : 1) * FB * 512];
    const int tid  = threadIdx.x;
    const int lane = tid & 63, w = tid >> 6;
    const int wr = w / WC, wc = w % WC;
    const int wg = xcd_swz(blockIdx.x, gridDim.x);
    const int m0 = (wg / NBX) * BM, n0 = (wg % NBX) * BN;
    const int g = lane >> 4, q = lane & 15;

    f32x4 acc[MR][NR] = {};

    // per-lane swizzled global base: row += q, col += g*8
    const bf16* gaA = A  + (long)(m0 + q) * K + g * 8;
    const bf16* gaB = Bt + (long)(n0 + q) * K + g * 8;

    auto stage = [&](int buf, int kt) {
#pragma unroll
        for (int fi = 0; fi < FA; fi++)
            if ((fi & 3) == w)
                gload16(gaA + (long)(fi >> 1) * 16 * K + kt + (fi & 1) * 32,
                        &Al[buf * FA * 512 + fi * 512]);
#pragma unroll
        for (int fi = 0; fi < FB; fi++)
            if ((fi & 3) == w)
                gload16(gaB + (long)(fi >> 1) * 16 * K + kt + (fi & 1) * 32,
                        &Bl[buf * FB * 512 + fi * 512]);
    };
    auto compute = [&](int buf) {
#pragma unroll
        for (int c = 0; c < 2; c++) {
            bf16x8 af[MR], bfr[NR];
#pragma unroll
            for (int i = 0; i < MR; i++)
                af[i] = *(const bf16x8*)
                    &Al[buf * FA * 512 + ((((wr * (BM / WR)) >> 4) + i) * 2 + c) * 512 + lane * 8];
#pragma unroll
            for (int i = 0; i < NR; i++)
                bfr[i] = *(const bf16x8*)
                    &Bl[buf * FB * 512 + ((((wc * (BN / WC)) >> 4) + i) * 2 + c) * 512 + lane * 8];
#pragma unroll
            for (int mi = 0; mi < MR; mi++)
#pragma unroll
                for (int ni = 0; ni < NR; ni++)
                    acc[mi][ni] = mfma16(af[mi], bfr[ni], acc[mi][ni]);
        }
    };

    if (DB) {
        stage(0, 0);
        __syncthreads();                       // tile 0 ready
        int cur = 0;
        for (int kt = 0; kt < K; kt += 64) {
            if (kt + 64 < K) stage(cur ^ 1, kt + 64);   // in flight under compute
            compute(cur);
            __syncthreads();                   // drains loads; protects cur
            cur ^= 1;
        }
    } else {
        for (int kt = 0; kt < K; kt += 64) {
            __syncthreads();
            stage(0, kt);
            __syncthreads();
            compute(0);
        }
    }

    // epilogue: C/D frag layout col = lane&15, row = (lane>>4)*4 + r
#pragma unroll
    for (int mi = 0; mi < MR; mi++) {
        if (EPI == 0) {
            // one wave spans exactly one head's 64 cols (BN/WC == 64)
            const int col0  = n0 + wc * 64;
            const int which = (col0 >= 1536) ? 2 : (col0 >= 768 ? 1 : 0);
            const int row0  = m0 + wr * (BM / WR) + mi * 16 + g * 4;
            float val[NR][4];
#pragma unroll
            for (int ni = 0; ni < NR; ni++) {
                const int dd = col0 + ni * 16 + q - which * 768;
                const float bias = (which == 0 ? bias0 : which == 1 ? bias1 : bias2)[dd];
#pragma unroll
                for (int r = 0; r < 4; r++) val[ni][r] = acc[mi][ni][r] + bias;
            }
            if (which <= 1) {   // fused per-row L2 norm over the head's 64 dims
#pragma unroll
                for (int r = 0; r < 4; r++) {
                    float ss = val[0][r] * val[0][r];
#pragma unroll
                    for (int ni = 1; ni < NR; ni++) ss += val[ni][r] * val[ni][r];
                    ss += __shfl_xor(ss, 1);
                    ss += __shfl_xor(ss, 2);
                    ss += __shfl_xor(ss, 4);
                    ss += __shfl_xor(ss, 8);
                    const float rn = 1.0f / fmaxf(sqrtf(ss), 1e-12f);
#pragma unroll
                    for (int ni = 0; ni < NR; ni++) val[ni][r] *= rn;
                }
            }
            const int dd0 = col0 - which * 768;
            const int hh  = dd0 >> 6;
            const long bh = (long)(row0 >> 11) * 12 + hh;
#pragma unroll
            for (int ni = 0; ni < NR; ni++) {
                const int dk = ni * 16 + q;
                if (which == 2) {
                    bf16x4 pv;
#pragma unroll
                    for (int r = 0; r < 4; r++) pv[r] = (bf16)val[ni][r];
                    *(bf16x4*)&vo[(bh * 64 + dk) * 2048 + (row0 & 2047)] = pv;
                } else {
                    bf16* dst = (which == 0) ? qo : ko;
#pragma unroll
                    for (int r = 0; r < 4; r++)
                        dst[(bh * 2048 + ((row0 + r) & 2047)) * 64 + dk] = (bf16)val[ni][r];
                }
            }
        } else {
#pragma unroll
            for (int ni = 0; ni < NR; ni++) {
                const int col  = n0 + wc * (BN / WC) + ni * 16 + q;
                const int row0 = m0 + wr * (BM / WR) + mi * 16 + g * 4;
                const float bias = bias0[col];
                if (EPI == 1) {          // + fp32 residual -> bf16
#pragma unroll
                    for (int r = 0; r < 4; r++) {
                        const int row = row0 + r;
                        outb[(long)row * 768 + col] =
                            (bf16)(acc[mi][ni][r] + bias + residf[(long)row * 768 + col]);
                    }
                } else if (EPI == 3) {   // + bf16 residual -> bf16
#pragma unroll
                    for (int r = 0; r < 4; r++) {
                        const int row = row0 + r;
                        outb[(long)row * 768 + col] =
                            (bf16)(acc[mi][ni][r] + bias + (float)residb[(long)row * 768 + col]);
                    }
                } else {                 // EPI == 2: exact GELU -> bf16
#pragma unroll
                    for (int r = 0; r < 4; r++) {
                        const float v  = acc[mi][ni][r] + bias;
                        const float gl = 0.5f * v * (1.0f + erff(v * 0.70710678118654752f));
                        outb[(long)(row0 + r) * 3072 + col] = (bf16)gl;
                    }
                }
            }
        }
    }
}

// ---------------------------------------------------------------------------
// Attention (no softmax): O = (Qn Kn^T)^2 @ V  per (b,h).
// Block = 4 waves x 16 q-rows = 64 q-rows; 64-key tiles; dbuf LDS staging,
// one barrier per tile, named A/B register sets, loop unrolled x2.
// Swapped QK^T -> P k-contiguous in wave-private padded LDS -> PV A-frag.
// 1D grid + XCD swizzle (same-bh blocks share K/V in one XCD L2).
// ---------------------------------------------------------------------------
__global__ __launch_bounds__(256, 2)
void attn_kernel(const bf16* __restrict__ Qn, const bf16* __restrict__ Kn,
                 const bf16* __restrict__ Vt, bf16* __restrict__ AO) {
    const int wg  = xcd_swz(blockIdx.x, gridDim.x);
    const int bh  = wg >> 5;
    const int tid = threadIdx.x, lane = tid & 63, w = tid >> 6;
    const int g = lane >> 4, q15 = lane & 15;
    const int qbase = (wg & 31) * 64 + w * 16;

    __shared__ __align__(16) bf16 Kl[2][64][72];
    __shared__ __align__(16) bf16 Vl[2][64][72];
    __shared__ __align__(16) bf16 Pl[4][16][72];
    bf16 (*Pw)[72] = Pl[w];

    const bf16* Qp = Qn + (long)bh * S_ * 64;
    const bf16* Kp = Kn + (long)bh * S_ * 64;
    const bf16* Vp = Vt + (long)bh * 64 * S_;

    const int srow = tid >> 3, scol = (tid & 7) * 8;   // staging coords

    bf16x8 qf0 = *(const bf16x8*)&Qp[(long)(qbase + q15) * 64 + g * 8];
    bf16x8 qf1 = *(const bf16x8*)&Qp[(long)(qbase + q15) * 64 + 32 + g * 8];

    f32x4 o[4] = {};

    bf16x8 aK0, aK1, aV0, aV1, bK0, bK1, bV0, bV1;
    auto gloadA = [&](int kt) {
        aK0 = *(const bf16x8*)&Kp[(long)(kt + srow) * 64 + scol];
        aK1 = *(const bf16x8*)&Kp[(long)(kt + 32 + srow) * 64 + scol];
        aV0 = *(const bf16x8*)&Vp[(long)srow * S_ + kt + scol];
        aV1 = *(const bf16x8*)&Vp[(long)(32 + srow) * S_ + kt + scol];
    };
    auto gloadB = [&](int kt) {
        bK0 = *(const bf16x8*)&Kp[(long)(kt + srow) * 64 + scol];
        bK1 = *(const bf16x8*)&Kp[(long)(kt + 32 + srow) * 64 + scol];
        bV0 = *(const bf16x8*)&Vp[(long)srow * S_ + kt + scol];
        bV1 = *(const bf16x8*)&Vp[(long)(32 + srow) * S_ + kt + scol];
    };
    auto stageA = [&](int buf) {
        *(bf16x8*)&Kl[buf][srow][scol]      = aK0;
        *(bf16x8*)&Kl[buf][32 + srow][scol] = aK1;
        *(bf16x8*)&Vl[buf][srow][scol]      = aV0;
        *(bf16x8*)&Vl[buf][32 + srow][scol] = aV1;
    };
    auto stageB = [&](int buf) {
        *(bf16x8*)&Kl[buf][srow][scol]      = bK0;
        *(bf16x8*)&Kl[buf][32 + srow][scol] = bK1;
        *(bf16x8*)&Vl[buf][srow][scol]      = bV0;
        *(bf16x8*)&Vl[buf][32 + srow][scol] = bV1;
    };

    auto compute = [&](int cur) {
        bf16x8 kf[4][2];
#pragma unroll
        for (int ni = 0; ni < 4; ni++)
#pragma unroll
            for (int c = 0; c < 2; c++)
                kf[ni][c] = *(const bf16x8*)&Kl[cur][ni * 16 + q15][c * 32 + g * 8];
        f32x4 s[4];
#pragma unroll
        for (int ni = 0; ni < 4; ni++) {
            s[ni] = mfma16(kf[ni][0], qf0, f32x4{0.f, 0.f, 0.f, 0.f});
            s[ni] = mfma16(kf[ni][1], qf1, s[ni]);
        }
#pragma unroll
        for (int ni = 0; ni < 4; ni++) {
            bf16x4 p4;
#pragma unroll
            for (int r = 0; r < 4; r++) { float v = s[ni][r]; p4[r] = (bf16)(v * v); }
            *(bf16x4*)&Pw[q15][ni * 16 + g * 4] = p4;
        }
        bf16x8 pf0 = *(const bf16x8*)&Pw[q15][g * 8];
        bf16x8 pf1 = *(const bf16x8*)&Pw[q15][32 + g * 8];
        bf16x8 vf[4][2];
#pragma unroll
        for (int ni = 0; ni < 4; ni++)
#pragma unroll
            for (int c = 0; c < 2; c++)
                vf[ni][c] = *(const bf16x8*)&Vl[cur][ni * 16 + q15][c * 32 + g * 8];
#pragma unroll
        for (int ni = 0; ni < 4; ni++) {
            o[ni] = mfma16(pf0, vf[ni][0], o[ni]);
            o[ni] = mfma16(pf1, vf[ni][1], o[ni]);
        }
    };

    gloadA(0);
    stageA(0);
    gloadB(64);
    __syncthreads();
    for (int t = 0; t <= 28; t += 2) {
        stageB(1);
        gloadA((t + 2) * 64);
        compute(0);
        __syncthreads();
        stageA(0);
        if (t + 3 < 32) gloadB((t + 3) * 64);
        compute(1);
        __syncthreads();
    }
    stageB(1);
    compute(0);
    __syncthreads();
    compute(1);

    const int b = bh / 12, h = bh % 12;
#pragma unroll
    for (int ni = 0; ni < 4; ni++)
#pragma unroll
        for (int r = 0; r < 4; r++) {
            const int s = qbase + g * 4 + r;
            AO[((long)b * S_ + s) * D_ + h * 64 + ni * 16 + q15] = (bf16)o[ni][r];
        }
}

// ---------------------------------------------------------------------------
// LayerNorm over D=768 (bf16 input). One block per row, 256 threads.
// WB=true: write bf16 only (mid-layer). WB=false: write fp32 (final out).
// ---------------------------------------------------------------------------
template<bool WB>
__global__ __launch_bounds__(256)
void ln_kernel(const bf16* __restrict__ y, const float* __restrict__ gamma,
               const float* __restrict__ beta, float* __restrict__ xo,
               bf16* __restrict__ xob) {
    __shared__ float sa[4], sb[4];
    const int row = blockIdx.x, t = threadIdx.x;
    const bf16* yr = y + (long)row * 768;
    float v0 = (float)yr[t], v1 = (float)yr[t + 256], v2 = (float)yr[t + 512];
    float s  = v0 + v1 + v2;
    float ss = v0 * v0 + v1 * v1 + v2 * v2;
#pragma unroll
    for (int o = 32; o; o >>= 1) { s += __shfl_xor(s, o); ss += __shfl_xor(ss, o); }
    if ((t & 63) == 0) { sa[t >> 6] = s; sb[t >> 6] = ss; }
    __syncthreads();
    s  = sa[0] + sa[1] + sa[2] + sa[3];
    ss = sb[0] + sb[1] + sb[2] + sb[3];
    const float mu   = s * (1.0f / 768.0f);
    const float var  = ss * (1.0f / 768.0f) - mu * mu;
    const float rstd = rsqrtf(var + 1e-5f);
#pragma unroll
    for (int i = 0; i < 3; i++) {
        const int c = t + i * 256;
        const float vv = (i == 0) ? v0 : (i == 1) ? v1 : v2;
        const float ov = (vv - mu) * rstd * gamma[c] + beta[c];
        if (WB) xob[(long)row * 768 + c] = (bf16)ov;
        else    xo[(long)row * 768 + c] = ov;
    }
}

// ---------------------------------------------------------------------------
extern "C" void kernel_launch(void* const* d_in, const int* in_sizes, int n_in,
                              void* d_out, int out_size, void* d_ws, size_t ws_size,
                              hipStream_t stream) {
    const float* x     = (const float*)d_in[0];
    const float* Wq    = (const float*)d_in[1];
    const float* bq    = (const float*)d_in[2];
    const float* Wk    = (const float*)d_in[3];
    const float* bk    = (const float*)d_in[4];
    const float* Wv    = (const float*)d_in[5];
    const float* bv    = (const float*)d_in[6];
    const float* Wo    = (const float*)d_in[7];
    const float* bo    = (const float*)d_in[8];
    const float* W1    = (const float*)d_in[9];
    const float* b1    = (const float*)d_in[10];
    const float* W2    = (const float*)d_in[11];
    const float* b2    = (const float*)d_in[12];
    const float* gamma = (const float*)d_in[13];
    const float* beta  = (const float*)d_in[14];

    char* p = (char*)d_ws;
    auto alloc = [&](size_t bytes) -> void* {
        void* r = p;
        p += (bytes + 255) & ~(size_t)255;
        return r;
    };
    bf16*  Xb    = (bf16*)alloc((size_t)M_ * D_ * 2);
    bf16*  Wqkvt = (bf16*)alloc((size_t)2304 * 768 * 2);
    bf16*  Wot   = (bf16*)alloc((size_t)768 * 768 * 2);
    bf16*  W1t   = (bf16*)alloc((size_t)3072 * 768 * 2);
    bf16*  W2t   = (bf16*)alloc((size_t)768 * 3072 * 2);
    bf16*  Qh    = (bf16*)alloc((size_t)BH_ * S_ * 64 * 2);
    bf16*  Kh    = (bf16*)alloc((size_t)BH_ * S_ * 64 * 2);
    bf16*  Vt    = (bf16*)alloc((size_t)BH_ * S_ * 64 * 2);
    bf16*  AO    = (bf16*)alloc((size_t)M_ * D_ * 2);
    bf16*  y1b   = (bf16*)alloc((size_t)M_ * D_ * 2);
    bf16*  x1b   = (bf16*)alloc((size_t)M_ * D_ * 2);
    bf16*  hbuf  = (bf16*)alloc((size_t)M_ * DFF_ * 2);
    bf16*  y2b   = y1b;  // y1b dead after LN1

    // pack + transpose weights (one launch)
    pack_x_kernel<<<(M_ * D_) / 1024, 256, 0, stream>>>(x, Xb);
    wt_all_kernel<<<1728, 256, 0, stream>>>(Wq, Wk, Wv, Wo, W1, W2,
                                            Wqkvt, Wot, W1t, W2t);

    // QKV projection (+fused Q/K L2-norm) -> Qh/Kh [bh][s][dk], Vt [bh][dk][s]
    gemm_bt<0, 768, 128, 128, 2, 2, false><<<18 * 32, 256, 0, stream>>>(
        Xb, Wqkvt, bq, bk, bv, nullptr, nullptr, nullptr, Qh, Kh, Vt);

    // attention
    attn_kernel<<<32 * BH_, 256, 0, stream>>>(Qh, Kh, Vt, AO);

    // out projection + residual -> bf16, LN1  (64x64 dbuf, 768 blocks)
    gemm_bt<1, 768, 64, 64, 2, 2, true><<<12 * 64, 256, 0, stream>>>(
        AO, Wot, bo, nullptr, nullptr, x, nullptr, y1b, nullptr, nullptr, nullptr);
    ln_kernel<true><<<M_, 256, 0, stream>>>(y1b, gamma, beta, nullptr, x1b);

    // FFN
    gemm_bt<2, 768, 128, 128, 2, 2, false><<<24 * 32, 256, 0, stream>>>(
        x1b, W1t, b1, nullptr, nullptr, nullptr, nullptr, hbuf, nullptr, nullptr, nullptr);
    gemm_bt<3, 3072, 64, 64, 2, 2, true><<<12 * 64, 256, 0, stream>>>(
        hbuf, W2t, b2, nullptr, nullptr, nullptr, x1b, y2b, nullptr, nullptr, nullptr);
    ln_kernel<false><<<M_, 256, 0, stream>>>(y2b, gamma, beta, (float*)d_out, nullptr);
}